// Round 3
// baseline (317.574 us; speedup 1.0000x reference)
//
#include <hip/hip_runtime.h>
#include <hip/hip_bf16.h>
#include <stdint.h>

typedef unsigned short u16;
typedef __attribute__((ext_vector_type(8))) short short8;
typedef __attribute__((ext_vector_type(4))) float f32x4;

#define NTRACE 4096
#define TLEN   64
#define ISZ    64
#define HSZ    128

__device__ __forceinline__ float bf2f(u16 u) {
  union { uint32_t i; float f; } v; v.i = ((uint32_t)u) << 16; return v.f;
}
__device__ __forceinline__ u16 f2bf(float f) {
  union { float f; uint32_t i; } v; v.f = f;
  uint32_t r = v.i + 0x7fffu + ((v.i >> 16) & 1u);
  return (u16)(r >> 16);
}
__device__ __forceinline__ float sigm(float x) { return 1.0f / (1.0f + __expf(-x)); }
__device__ __forceinline__ float tanh_(float x) { float e = __expf(2.0f * x); return 1.0f - 2.0f / (e + 1.0f); }

// Load 8 consecutive f32 and pack to a bf16 MFMA fragment (RNE).
__device__ __forceinline__ short8 load8f(const float* __restrict__ p) {
  f32x4 a = *(const f32x4*)(p);
  f32x4 b = *(const f32x4*)(p + 4);
  short8 r;
  r[0] = (short)f2bf(a[0]); r[1] = (short)f2bf(a[1]);
  r[2] = (short)f2bf(a[2]); r[3] = (short)f2bf(a[3]);
  r[4] = (short)f2bf(b[0]); r[5] = (short)f2bf(b[1]);
  r[6] = (short)f2bf(b[2]); r[7] = (short)f2bf(b[3]);
  return r;
}

// ---------------------------------------------------------------------------
// Fully fused per-trace kernel. One wave (64 lanes) per trace; block = 4 waves
// = 4 traces. LDS: 16 KB/wave h-buffer (bf16), reused for h1 then h2, then
// overlaid by per-wave trace-embedding staging (first 2 KB).
//
// MFMA (transposed orientation): D = A*B, A = weight rows
// (A[m=lane&15][k=q*8+j]), B = x^T (B[k=q*8+j][n=token=lane&15]),
// D[m = h = q*4+r][n = token = lane&15]. f-gate skipped (c0 = 0).
// All global float tensors are FP32; converted to bf16 in registers.
// ---------------------------------------------------------------------------
__global__ __launch_bounds__(256) void k_fused(
    const float* __restrict__ emb,
    const float* __restrict__ W1, const float* __restrict__ b_ih1, const float* __restrict__ b_hh1,
    const float* __restrict__ W2, const float* __restrict__ b_ih2, const float* __restrict__ b_hh2,
    const float* __restrict__ Wp1, const float* __restrict__ bp1v,
    const float* __restrict__ Wp2, const float* __restrict__ bp2v,
    const int* __restrict__ traces, const int* __restrict__ lengths,
    float* __restrict__ fin)
{
  __shared__ u16 hbuf[4][TLEN][HSZ];   // 64 KB

  const int lane = threadIdx.x & 63;
  const int w    = threadIdx.x >> 6;
  const int col  = lane & 15;
  const int q    = lane >> 4;
  const int t    = blockIdx.x * 4 + w;
  const int len  = lengths[t];

  const f32x4 z = {0.f, 0.f, 0.f, 0.f};

  // ---- x fragments (B-operand of lstm1)
  short8 xf[4][2];
#pragma unroll
  for (int g = 0; g < 4; ++g) {
    const int tok = traces[t * TLEN + g * 16 + col];
    const float* xr = emb + (size_t)tok * ISZ + q * 8;
    xf[g][0] = load8f(xr);
    xf[g][1] = load8f(xr + 32);
  }

  // ---- LSTM layer 1 (K = 64, 2 k-steps); gate rows: i@0, g@256, o@384
#pragma unroll
  for (int mt = 0; mt < 8; ++mt) {
    f32x4 accI[4], accC[4], accO[4];
#pragma unroll
    for (int g = 0; g < 4; ++g) { accI[g] = z; accC[g] = z; accO[g] = z; }
#pragma unroll
    for (int ks = 0; ks < 2; ++ks) {
      const float* wb = W1 + ks * 32 + q * 8;
      short8 fI = load8f(wb + (size_t)(mt * 16 + col) * ISZ);
      short8 fC = load8f(wb + (size_t)(256 + mt * 16 + col) * ISZ);
      short8 fO = load8f(wb + (size_t)(384 + mt * 16 + col) * ISZ);
#pragma unroll
      for (int g = 0; g < 4; ++g) {
        accI[g] = __builtin_amdgcn_mfma_f32_16x16x32_bf16(fI, xf[g][ks], accI[g], 0, 0, 0);
        accC[g] = __builtin_amdgcn_mfma_f32_16x16x32_bf16(fC, xf[g][ks], accC[g], 0, 0, 0);
        accO[g] = __builtin_amdgcn_mfma_f32_16x16x32_bf16(fO, xf[g][ks], accO[g], 0, 0, 0);
      }
    }
    float bI[4], bC[4], bO[4];
#pragma unroll
    for (int r = 0; r < 4; ++r) {
      const int h = mt * 16 + q * 4 + r;
      bI[r] = b_ih1[h]       + b_hh1[h];
      bC[r] = b_ih1[256 + h] + b_hh1[256 + h];
      bO[r] = b_ih1[384 + h] + b_hh1[384 + h];
    }
#pragma unroll
    for (int g = 0; g < 4; ++g) {
      u16 hv[4];
#pragma unroll
      for (int r = 0; r < 4; ++r) {
        float c = sigm(accI[g][r] + bI[r]) * tanh_(accC[g][r] + bC[r]);
        hv[r] = f2bf(sigm(accO[g][r] + bO[r]) * tanh_(c));
      }
      uint2 pk;
      pk.x = (uint32_t)hv[0] | ((uint32_t)hv[1] << 16);
      pk.y = (uint32_t)hv[2] | ((uint32_t)hv[3] << 16);
      *(uint2*)&hbuf[w][g * 16 + col][mt * 16 + q * 4] = pk;
    }
  }
  __syncthreads();

  // ---- load h1 fragments (B-operand of lstm2)
  short8 hf[4][4];
#pragma unroll
  for (int g = 0; g < 4; ++g)
#pragma unroll
    for (int ks = 0; ks < 4; ++ks)
      hf[g][ks] = *(const short8*)&hbuf[w][g * 16 + col][ks * 32 + q * 8];
  __syncthreads();   // all lanes hold h1 before hbuf is overwritten with h2

  // ---- LSTM layer 2 (K = 128, 4 k-steps)
#pragma unroll
  for (int mt = 0; mt < 8; ++mt) {
    f32x4 accI[4], accC[4], accO[4];
#pragma unroll
    for (int g = 0; g < 4; ++g) { accI[g] = z; accC[g] = z; accO[g] = z; }
#pragma unroll
    for (int ks = 0; ks < 4; ++ks) {
      const float* wb = W2 + ks * 32 + q * 8;
      short8 fI = load8f(wb + (size_t)(mt * 16 + col) * HSZ);
      short8 fC = load8f(wb + (size_t)(256 + mt * 16 + col) * HSZ);
      short8 fO = load8f(wb + (size_t)(384 + mt * 16 + col) * HSZ);
#pragma unroll
      for (int g = 0; g < 4; ++g) {
        accI[g] = __builtin_amdgcn_mfma_f32_16x16x32_bf16(fI, hf[g][ks], accI[g], 0, 0, 0);
        accC[g] = __builtin_amdgcn_mfma_f32_16x16x32_bf16(fC, hf[g][ks], accC[g], 0, 0, 0);
        accO[g] = __builtin_amdgcn_mfma_f32_16x16x32_bf16(fO, hf[g][ks], accO[g], 0, 0, 0);
      }
    }
    float bI[4], bC[4], bO[4];
#pragma unroll
    for (int r = 0; r < 4; ++r) {
      const int h = mt * 16 + q * 4 + r;
      bI[r] = b_ih2[h]       + b_hh2[h];
      bC[r] = b_ih2[256 + h] + b_hh2[256 + h];
      bO[r] = b_ih2[384 + h] + b_hh2[384 + h];
    }
#pragma unroll
    for (int g = 0; g < 4; ++g) {
      u16 hv[4];
#pragma unroll
      for (int r = 0; r < 4; ++r) {
        float c = sigm(accI[g][r] + bI[r]) * tanh_(accC[g][r] + bC[r]);
        hv[r] = f2bf(sigm(accO[g][r] + bO[r]) * tanh_(c));
      }
      uint2 pk;
      pk.x = (uint32_t)hv[0] | ((uint32_t)hv[1] << 16);
      pk.y = (uint32_t)hv[2] | ((uint32_t)hv[3] << 16);
      *(uint2*)&hbuf[w][g * 16 + col][mt * 16 + q * 4] = pk;
    }
  }
  __syncthreads();

  // ---- reload fragments: now h2
#pragma unroll
  for (int g = 0; g < 4; ++g)
#pragma unroll
    for (int ks = 0; ks < 4; ++ks)
      hf[g][ks] = *(const short8*)&hbuf[w][g * 16 + col][ks * 32 + q * 8];

  // ---- attention-MLP energy: p = relu(h2 @ Wp1.T + bp1); e = p @ Wp2 + bp2
  float ep[4] = {0.f, 0.f, 0.f, 0.f};
#pragma unroll
  for (int mt = 0; mt < 4; ++mt) {
    f32x4 acc[4];
#pragma unroll
    for (int g = 0; g < 4; ++g) acc[g] = z;
#pragma unroll
    for (int ks = 0; ks < 4; ++ks) {
      short8 fA = load8f(Wp1 + (size_t)(mt * 16 + col) * HSZ + ks * 32 + q * 8);
#pragma unroll
      for (int g = 0; g < 4; ++g)
        acc[g] = __builtin_amdgcn_mfma_f32_16x16x32_bf16(fA, hf[g][ks], acc[g], 0, 0, 0);
    }
#pragma unroll
    for (int r = 0; r < 4; ++r) {
      const int hp = mt * 16 + q * 4 + r;
      const float b1 = bp1v[hp];
      const float w2 = Wp2[hp];
#pragma unroll
      for (int g = 0; g < 4; ++g)
        ep[g] += fmaxf(acc[g][r] + b1, 0.f) * w2;
    }
  }
  // sum the q-partials: lanes col, col+16, col+32, col+48
#pragma unroll
  for (int g = 0; g < 4; ++g) {
    ep[g] += __shfl_xor(ep[g], 16);
    ep[g] += __shfl_xor(ep[g], 32);
  }
  const float bp2f = bp2v[0];

  // ---- masked softmax over the 64 positions (token l = g*16 + col)
  float e[4]; bool val[4];
  float m = -3.0e38f;
#pragma unroll
  for (int g = 0; g < 4; ++g) {
    const int l = g * 16 + col;
    val[g] = l < len;
    e[g] = ep[g] + bp2f;
    m = fmaxf(m, val[g] ? e[g] : -3.0e38f);
  }
  m = fmaxf(m, __shfl_xor(m, 1));
  m = fmaxf(m, __shfl_xor(m, 2));
  m = fmaxf(m, __shfl_xor(m, 4));
  m = fmaxf(m, __shfl_xor(m, 8));
  float wgt[4], s = 0.f;
#pragma unroll
  for (int g = 0; g < 4; ++g) {
    wgt[g] = val[g] ? __expf(e[g] - m) : 0.f;
    s += wgt[g];
  }
  s += __shfl_xor(s, 1);
  s += __shfl_xor(s, 2);
  s += __shfl_xor(s, 4);
  s += __shfl_xor(s, 8);
  const float inv = 1.0f / s;
#pragma unroll
  for (int g = 0; g < 4; ++g) wgt[g] *= inv;

  // ---- weighted sum over positions: te[h] = sum_l wgt[l] * h2[l][h]
  // lane handles h = 4*(lane&31)..+3; positions l = 2*i + (lane>>5).
  const int half = lane >> 5;
  const int hb   = (lane & 31) * 4;
  float a4[4] = {0.f, 0.f, 0.f, 0.f};
#pragma unroll
  for (int i = 0; i < 32; ++i) {
    const int l = 2 * i + half;
    const float wl = __shfl(wgt[i >> 3], l & 15, 64);  // (2i+half)>>4 == i>>3
    const uint2 hv = *(const uint2*)&hbuf[w][l][hb];
    a4[0] += wl * bf2f((u16)(hv.x & 0xffffu));
    a4[1] += wl * bf2f((u16)(hv.x >> 16));
    a4[2] += wl * bf2f((u16)(hv.y & 0xffffu));
    a4[3] += wl * bf2f((u16)(hv.y >> 16));
  }
#pragma unroll
  for (int k = 0; k < 4; ++k) a4[k] += __shfl_xor(a4[k], 32);

  __syncthreads();                    // everyone done READING hbuf
  float* teb = (float*)hbuf;          // overlay: 4 waves x 128 floats = 2 KB
  if (half == 0) {
#pragma unroll
    for (int k = 0; k < 4; ++k) teb[w * HSZ + hb + k] = a4[k];
  }
  __syncthreads();

  // ---- block-level sum over the 4 traces, one atomic per h per block
  if (threadIdx.x < HSZ) {
    const int h = threadIdx.x;
    const float ssum = teb[h] + teb[HSZ + h] + teb[2 * HSZ + h] + teb[3 * HSZ + h];
    atomicAdd(&fin[h], ssum);
  }
}

__global__ __launch_bounds__(128) void k_zero(float* __restrict__ fin)
{
  fin[threadIdx.x] = 0.f;
}

// out = final @ W_out.T + b_out   (128x128, one block, all FP32)
__global__ __launch_bounds__(128) void k_out(
    const float* __restrict__ fin, const float* __restrict__ W_out,
    const float* __restrict__ b_out, float* __restrict__ out)
{
  const int o = threadIdx.x;
  __shared__ float fs[HSZ];
  fs[o] = fin[o];
  __syncthreads();
  float acc = b_out[o];
  const float* wr = W_out + (size_t)o * HSZ;
#pragma unroll
  for (int h = 0; h < HSZ; ++h) acc += wr[h] * fs[h];
  out[o] = acc;
}

extern "C" void kernel_launch(void* const* d_in, const int* in_sizes, int n_in,
                              void* d_out, int out_size, void* d_ws, size_t ws_size,
                              hipStream_t stream)
{
  const float* emb   = (const float*)d_in[0];
  const float* W_ih1 = (const float*)d_in[1];
  // d_in[2] = W_hh1: unused (h0 = 0)
  const float* b_ih1 = (const float*)d_in[3];
  const float* b_hh1 = (const float*)d_in[4];
  const float* W_ih2 = (const float*)d_in[5];
  // d_in[6] = W_hh2: unused
  const float* b_ih2 = (const float*)d_in[7];
  const float* b_hh2 = (const float*)d_in[8];
  const float* Wp1   = (const float*)d_in[9];
  const float* bp1   = (const float*)d_in[10];
  const float* Wp2   = (const float*)d_in[11];
  const float* bp2   = (const float*)d_in[12];
  const float* W_out = (const float*)d_in[13];
  const float* b_out = (const float*)d_in[14];
  const int* traces  = (const int*)d_in[15];
  const int* lengths = (const int*)d_in[16];

  float* fin = (float*)d_ws;   // 128 floats = 512 B total workspace

  k_zero<<<1, 128, 0, stream>>>(fin);
  k_fused<<<NTRACE / 4, 256, 0, stream>>>(emb, W_ih1, b_ih1, b_hh1,
                                          W_ih2, b_ih2, b_hh2,
                                          Wp1, bp1, Wp2, bp2,
                                          traces, lengths, fin);
  k_out<<<1, 128, 0, stream>>>(fin, W_out, b_out, (float*)d_out);
}